// Round 10
// baseline (555.521 us; speedup 1.0000x reference)
//
#include <hip/hip_runtime.h>
#include <math.h>

// Problem constants: B=32, S=4096, H=768.
constexpr int B = 32;
constexpr int S = 4096;
constexpr int H = 768;

constexpr int BPB   = 64;                  // partial blocks per batch
constexpr int NPART = B * BPB;             // 2048 blocks
constexpr int WPB   = BPB * 4;             // waves per batch = 256
constexpr int RPW   = S / WPB;             // rows per wave = 16

typedef float f4 __attribute__((ext_vector_type(4)));

// ---------------------------------------------------------------------------
// Kernel 1: fused score + softmax-weighted pooling + per-batch combine.
// R7 NT streaming body (best measured: 4.5 TB/s read). After publishing its
// partial, the last-arriving block of each batch (device-scope counter)
// combines the 64 partials and writes context[b] — kernel 2 eliminated.
// ---------------------------------------------------------------------------
__global__ __launch_bounds__(256, 6)
void pool_partial(const float* __restrict__ hs,
                  const int*   __restrict__ mask,
                  const int*   __restrict__ boost,
                  const float* __restrict__ attn_w,
                  const float* __restrict__ attn_b,
                  float* __restrict__ pl, float* __restrict__ pc,
                  int* __restrict__ pcount, float* __restrict__ context)
{
    const int blk  = blockIdx.x;            // 0..2047
    const int b    = blk >> 6;              // batch
    const int kb   = blk & (BPB - 1);
    const int tid  = threadIdx.x;
    const int w    = tid >> 6;              // wave in block
    const int lane = tid & 63;
    const int W    = kb * 4 + w;            // wave index within batch [0,256)

    f4 wv[3];
#pragma unroll
    for (int j = 0; j < 3; ++j)
        wv[j] = *reinterpret_cast<const f4*>(attn_w + 256 * j + 4 * lane);
    const float bias = attn_b[0];

    // per-row meta for row s = 16W + lane (lane < 16):
    //   p = exp((d + bias) * mult + madd); masked rows -> madd=-1e30 -> p=0
    float mult0 = 0.0f, madd0 = -1e30f;
    if (lane < RPW) {
        const int s  = W * RPW + lane;
        const int mk = mask[(size_t)b * S + s];
        const float bs = (float)boost[(size_t)b * S + s];
        mult0 = mk ? (1.0f + 2.0f * bs) : 0.0f;
        madd0 = mk ? -16.0f : -1e30f;
    }

    float l = 0.0f;
    f4 c[3];
#pragma unroll
    for (int j = 0; j < 3; ++j) c[j] = (f4)(0.0f);

    const float* base = hs + (size_t)b * S * H;

    for (int t = 0; t < RPW; t += 2) {
        const float* rA = base + (size_t)(W * RPW + t) * H;   // row 16W+t
        const float* rB = rA + H;                             // row 16W+t+1

        const f4 a0 = __builtin_nontemporal_load(reinterpret_cast<const f4*>(rA) + lane);
        const f4 a1 = __builtin_nontemporal_load(reinterpret_cast<const f4*>(rA) + 64 + lane);
        const f4 a2 = __builtin_nontemporal_load(reinterpret_cast<const f4*>(rA) + 128 + lane);
        const f4 b0 = __builtin_nontemporal_load(reinterpret_cast<const f4*>(rB) + lane);
        const f4 b1 = __builtin_nontemporal_load(reinterpret_cast<const f4*>(rB) + 64 + lane);
        const f4 b2 = __builtin_nontemporal_load(reinterpret_cast<const f4*>(rB) + 128 + lane);

        float dA = (a0.x * wv[0].x + a1.x * wv[1].x + a2.x * wv[2].x)
                 + (a0.y * wv[0].y + a1.y * wv[1].y + a2.y * wv[2].y)
                 + (a0.z * wv[0].z + a1.z * wv[1].z + a2.z * wv[2].z)
                 + (a0.w * wv[0].w + a1.w * wv[1].w + a2.w * wv[2].w);
        float dB = (b0.x * wv[0].x + b1.x * wv[1].x + b2.x * wv[2].x)
                 + (b0.y * wv[0].y + b1.y * wv[1].y + b2.y * wv[2].y)
                 + (b0.z * wv[0].z + b1.z * wv[1].z + b2.z * wv[2].z)
                 + (b0.w * wv[0].w + b1.w * wv[1].w + b2.w * wv[2].w);
#pragma unroll
        for (int off = 32; off >= 1; off >>= 1) {
            dA += __shfl_xor(dA, off, 64);
            dB += __shfl_xor(dB, off, 64);
        }

        const float mA  = __shfl(mult0, t, 64);
        const float adA = __shfl(madd0, t, 64);
        const float mB  = __shfl(mult0, t + 1, 64);
        const float adB = __shfl(madd0, t + 1, 64);
        const float pA  = __expf(fmaf(dA + bias, mA, adA));
        const float pB  = __expf(fmaf(dB + bias, mB, adB));

        l += pA + pB;
        c[0] = c[0] + pA * a0 + pB * b0;
        c[1] = c[1] + pA * a1 + pB * b1;
        c[2] = c[2] + pA * a2 + pB * b2;
    }

    // intra-block combine: plain sums
    __shared__ float sl[4];
    __shared__ float scmb[4][H];
    __shared__ int   slast;
#pragma unroll
    for (int j = 0; j < 3; ++j)
        *reinterpret_cast<f4*>(&scmb[w][256 * j + 4 * lane]) = c[j];
    if (lane == 0) sl[w] = l;
    __syncthreads();

    if (tid == 0) pl[blk] = (sl[0] + sl[1]) + (sl[2] + sl[3]);
#pragma unroll
    for (int q = 0; q < 3; ++q) {
        const int h = tid + q * 256;
        pc[(size_t)blk * H + h] =
            (scmb[0][h] + scmb[1][h]) + (scmb[2][h] + scmb[3][h]);
    }

    // publish + elect the last block of this batch (device-scope)
    __threadfence();
    __syncthreads();
    if (tid == 0) {
        const int old = __hip_atomic_fetch_add(&pcount[b], 1,
                                               __ATOMIC_ACQ_REL,
                                               __HIP_MEMORY_SCOPE_AGENT);
        slast = (old == BPB - 1);
    }
    __syncthreads();
    if (!slast) return;

    // last block: combine 64 partials -> context[b][:]
    __shared__ float sinv;
    if (tid < 64) {
        float lv = pl[b * BPB + tid];
#pragma unroll
        for (int off = 32; off >= 1; off >>= 1)
            lv += __shfl_xor(lv, off, 64);
        if (tid == 0) sinv = 1.0f / lv;
    }
    __syncthreads();

#pragma unroll
    for (int q = 0; q < 3; ++q) {
        const int h = tid + q * 256;
        float a0 = 0.f, a1 = 0.f, a2 = 0.f, a3 = 0.f;
#pragma unroll 4
        for (int i = 0; i < BPB; i += 4) {
            a0 += pc[((size_t)b * BPB + i + 0) * H + h];
            a1 += pc[((size_t)b * BPB + i + 1) * H + h];
            a2 += pc[((size_t)b * BPB + i + 2) * H + h];
            a3 += pc[((size_t)b * BPB + i + 3) * H + h];
        }
        context[b * H + h] = ((a0 + a1) + (a2 + a3)) * sinv;
    }
}

// ---------------------------------------------------------------------------
// Kernel 2: fused BatchNorm + FC + residual + ReLU.
// ---------------------------------------------------------------------------
__global__ __launch_bounds__(256)
void fc_bn_relu(const float* __restrict__ context,
                const float* __restrict__ gamma, const float* __restrict__ beta,
                const float* __restrict__ fcw,  const float* __restrict__ fcb,
                float* __restrict__ out)
{
    const int qc  = blockIdx.x;   // 0..2
    const int b   = blockIdx.y;   // 0..31
    const int tid = threadIdx.x;

    __shared__ float ch[H];       // chat[b][:]

#pragma unroll
    for (int q = 0; q < 3; ++q) {
        const int h = tid + q * 256;
        float mean = 0.0f;
#pragma unroll
        for (int bb = 0; bb < B; ++bb) mean += context[bb * H + h];
        mean *= (1.0f / B);
        float var = 0.0f;
#pragma unroll
        for (int bb = 0; bb < B; ++bb) {
            const float d = context[bb * H + h] - mean;
            var = fmaf(d, d, var);
        }
        var *= (1.0f / B);
        const float inv = rsqrtf(var + 1e-5f);
        ch[h] = (context[b * H + h] - mean) * inv * gamma[h] + beta[h];
    }
    __syncthreads();

    const int i = qc * 256 + tid;                 // output column
    const f4* wr  = reinterpret_cast<const f4*>(fcw + (size_t)i * H);
    const f4* chv = reinterpret_cast<const f4*>(ch);

    float acc = fcb[i];
#pragma unroll 4
    for (int hq = 0; hq < H / 4; ++hq) {
        const f4 wvv = wr[hq];
        const f4 cv  = chv[hq];
        acc += wvv.x * cv.x + wvv.y * cv.y + wvv.z * cv.z + wvv.w * cv.w;
    }
    acc += ch[i];
    out[(size_t)b * H + i] = fmaxf(acc, 0.0f);
}

// ---------------------------------------------------------------------------
extern "C" void kernel_launch(void* const* d_in, const int* in_sizes, int n_in,
                              void* d_out, int out_size, void* d_ws, size_t ws_size,
                              hipStream_t stream)
{
    const float* hs     = (const float*)d_in[0];
    const int*   mask   = (const int*)d_in[1];
    const int*   boost  = (const int*)d_in[2];
    const float* attn_w = (const float*)d_in[3];
    const float* attn_b = (const float*)d_in[4];
    const float* fc_w   = (const float*)d_in[5];
    const float* fc_b   = (const float*)d_in[6];
    const float* gamma  = (const float*)d_in[7];
    const float* beta   = (const float*)d_in[8];
    float* out = (float*)d_out;

    float* ws      = (float*)d_ws;
    float* pl      = ws;                          // [2048]
    float* pc      = pl + NPART;                  // [2048][768]
    float* context = pc + (size_t)NPART * H;      // [32][768]
    int*   pcount  = (int*)(context + B * H);     // [32]

    // reset per-batch arrival counters (graph-capturable async memset)
    hipMemsetAsync(pcount, 0, B * sizeof(int), stream);

    pool_partial<<<dim3(NPART), 256, 0, stream>>>(hs, mask, boost, attn_w, attn_b,
                                                  pl, pc, pcount, context);
    fc_bn_relu<<<dim3(H / 256, B), 256, 0, stream>>>(context, gamma, beta,
                                                     fc_w, fc_b, out);
}

// Round 11
// 101.479 us; speedup vs baseline: 5.4742x; 5.4742x over previous
//
#include <hip/hip_runtime.h>
#include <math.h>

// Problem constants: B=32, S=4096, H=768.
constexpr int B = 32;
constexpr int S = 4096;
constexpr int H = 768;

constexpr int BPB   = 64;                  // partial blocks per batch
constexpr int NPART = B * BPB;             // 2048 blocks
constexpr int WPB   = BPB * 4;             // waves per batch = 256
constexpr int RPW   = S / WPB;             // rows per wave = 16

typedef float f4 __attribute__((ext_vector_type(4)));

// ---------------------------------------------------------------------------
// Kernel 1: fused score + softmax-weighted pooling, one streaming pass.
// NT loads (bypass caches; single-touch stream). Fixed-reference softmax
// exp(score-16), branch-free. Contiguous per-wave mapping: wave W owns rows
// [16W, 16W+16) -> each 2-row iteration reads 6 KB fully contiguous.
// Best measured configuration (R7: 101.86 us).
// ---------------------------------------------------------------------------
__global__ __launch_bounds__(256, 6)
void pool_partial(const float* __restrict__ hs,
                  const int*   __restrict__ mask,
                  const int*   __restrict__ boost,
                  const float* __restrict__ attn_w,
                  const float* __restrict__ attn_b,
                  float* __restrict__ pl, float* __restrict__ pc)
{
    const int blk  = blockIdx.x;            // 0..2047
    const int b    = blk >> 6;              // batch
    const int kb   = blk & (BPB - 1);
    const int tid  = threadIdx.x;
    const int w    = tid >> 6;              // wave in block
    const int lane = tid & 63;
    const int W    = kb * 4 + w;            // wave index within batch [0,256)

    f4 wv[3];
#pragma unroll
    for (int j = 0; j < 3; ++j)
        wv[j] = *reinterpret_cast<const f4*>(attn_w + 256 * j + 4 * lane);
    const float bias = attn_b[0];

    // per-row meta for row s = 16W + lane (lane < 16):
    //   p = exp((d + bias) * mult + madd); masked rows -> madd=-1e30 -> p=0
    float mult0 = 0.0f, madd0 = -1e30f;
    if (lane < RPW) {
        const int s  = W * RPW + lane;
        const int mk = mask[(size_t)b * S + s];
        const float bs = (float)boost[(size_t)b * S + s];
        mult0 = mk ? (1.0f + 2.0f * bs) : 0.0f;
        madd0 = mk ? -16.0f : -1e30f;
    }

    float l = 0.0f;
    f4 c[3];
#pragma unroll
    for (int j = 0; j < 3; ++j) c[j] = (f4)(0.0f);

    const float* base = hs + (size_t)b * S * H;

    for (int t = 0; t < RPW; t += 2) {
        const float* rA = base + (size_t)(W * RPW + t) * H;   // row 16W+t
        const float* rB = rA + H;                             // row 16W+t+1

        const f4 a0 = __builtin_nontemporal_load(reinterpret_cast<const f4*>(rA) + lane);
        const f4 a1 = __builtin_nontemporal_load(reinterpret_cast<const f4*>(rA) + 64 + lane);
        const f4 a2 = __builtin_nontemporal_load(reinterpret_cast<const f4*>(rA) + 128 + lane);
        const f4 b0 = __builtin_nontemporal_load(reinterpret_cast<const f4*>(rB) + lane);
        const f4 b1 = __builtin_nontemporal_load(reinterpret_cast<const f4*>(rB) + 64 + lane);
        const f4 b2 = __builtin_nontemporal_load(reinterpret_cast<const f4*>(rB) + 128 + lane);

        float dA = (a0.x * wv[0].x + a1.x * wv[1].x + a2.x * wv[2].x)
                 + (a0.y * wv[0].y + a1.y * wv[1].y + a2.y * wv[2].y)
                 + (a0.z * wv[0].z + a1.z * wv[1].z + a2.z * wv[2].z)
                 + (a0.w * wv[0].w + a1.w * wv[1].w + a2.w * wv[2].w);
        float dB = (b0.x * wv[0].x + b1.x * wv[1].x + b2.x * wv[2].x)
                 + (b0.y * wv[0].y + b1.y * wv[1].y + b2.y * wv[2].y)
                 + (b0.z * wv[0].z + b1.z * wv[1].z + b2.z * wv[2].z)
                 + (b0.w * wv[0].w + b1.w * wv[1].w + b2.w * wv[2].w);
#pragma unroll
        for (int off = 32; off >= 1; off >>= 1) {
            dA += __shfl_xor(dA, off, 64);
            dB += __shfl_xor(dB, off, 64);
        }

        const float mA  = __shfl(mult0, t, 64);
        const float adA = __shfl(madd0, t, 64);
        const float mB  = __shfl(mult0, t + 1, 64);
        const float adB = __shfl(madd0, t + 1, 64);
        const float pA  = __expf(fmaf(dA + bias, mA, adA));
        const float pB  = __expf(fmaf(dB + bias, mB, adB));

        l += pA + pB;
        c[0] = c[0] + pA * a0 + pB * b0;
        c[1] = c[1] + pA * a1 + pB * b1;
        c[2] = c[2] + pA * a2 + pB * b2;
    }

    // intra-block combine: plain sums
    __shared__ float sl[4];
    __shared__ float scmb[4][H];
#pragma unroll
    for (int j = 0; j < 3; ++j)
        *reinterpret_cast<f4*>(&scmb[w][256 * j + 4 * lane]) = c[j];
    if (lane == 0) sl[w] = l;
    __syncthreads();

    if (tid == 0) pl[blk] = (sl[0] + sl[1]) + (sl[2] + sl[3]);
#pragma unroll
    for (int q = 0; q < 3; ++q) {
        const int h = tid + q * 256;
        pc[(size_t)blk * H + h] =
            (scmb[0][h] + scmb[1][h]) + (scmb[2][h] + scmb[3][h]);
    }
}

// ---------------------------------------------------------------------------
// Kernel 2: combine 64 partials per batch -> context[32][768]
// ---------------------------------------------------------------------------
__global__ __launch_bounds__(256)
void pool_combine(const float* __restrict__ pl, const float* __restrict__ pc,
                  float* __restrict__ context)
{
    const int qc  = blockIdx.x;
    const int b   = blockIdx.y;
    const int tid = threadIdx.x;
    __shared__ float sinv;

    if (tid < 64) {
        float lv = pl[b * BPB + tid];
#pragma unroll
        for (int off = 32; off >= 1; off >>= 1)
            lv += __shfl_xor(lv, off, 64);
        if (tid == 0) sinv = 1.0f / lv;
    }
    __syncthreads();

    const int h = qc * 256 + tid;
    float a0 = 0.f, a1 = 0.f, a2 = 0.f, a3 = 0.f;
#pragma unroll 4
    for (int i = 0; i < BPB; i += 4) {
        a0 += pc[((size_t)b * BPB + i + 0) * H + h];
        a1 += pc[((size_t)b * BPB + i + 1) * H + h];
        a2 += pc[((size_t)b * BPB + i + 2) * H + h];
        a3 += pc[((size_t)b * BPB + i + 3) * H + h];
    }
    context[b * H + h] = ((a0 + a1) + (a2 + a3)) * sinv;
}

// ---------------------------------------------------------------------------
// Kernel 3: fused BatchNorm + FC + residual + ReLU.
// ---------------------------------------------------------------------------
__global__ __launch_bounds__(256)
void fc_bn_relu(const float* __restrict__ context,
                const float* __restrict__ gamma, const float* __restrict__ beta,
                const float* __restrict__ fcw,  const float* __restrict__ fcb,
                float* __restrict__ out)
{
    const int qc  = blockIdx.x;   // 0..2
    const int b   = blockIdx.y;   // 0..31
    const int tid = threadIdx.x;

    __shared__ float ch[H];       // chat[b][:]

#pragma unroll
    for (int q = 0; q < 3; ++q) {
        const int h = tid + q * 256;
        float mean = 0.0f;
#pragma unroll
        for (int bb = 0; bb < B; ++bb) mean += context[bb * H + h];
        mean *= (1.0f / B);
        float var = 0.0f;
#pragma unroll
        for (int bb = 0; bb < B; ++bb) {
            const float d = context[bb * H + h] - mean;
            var = fmaf(d, d, var);
        }
        var *= (1.0f / B);
        const float inv = rsqrtf(var + 1e-5f);
        ch[h] = (context[b * H + h] - mean) * inv * gamma[h] + beta[h];
    }
    __syncthreads();

    const int i = qc * 256 + tid;                 // output column
    const f4* wr  = reinterpret_cast<const f4*>(fcw + (size_t)i * H);
    const f4* chv = reinterpret_cast<const f4*>(ch);

    float acc = fcb[i];
#pragma unroll 4
    for (int hq = 0; hq < H / 4; ++hq) {
        const f4 wvv = wr[hq];
        const f4 cv  = chv[hq];
        acc += wvv.x * cv.x + wvv.y * cv.y + wvv.z * cv.z + wvv.w * cv.w;
    }
    acc += ch[i];
    out[(size_t)b * H + i] = fmaxf(acc, 0.0f);
}

// ---------------------------------------------------------------------------
extern "C" void kernel_launch(void* const* d_in, const int* in_sizes, int n_in,
                              void* d_out, int out_size, void* d_ws, size_t ws_size,
                              hipStream_t stream)
{
    const float* hs     = (const float*)d_in[0];
    const int*   mask   = (const int*)d_in[1];
    const int*   boost  = (const int*)d_in[2];
    const float* attn_w = (const float*)d_in[3];
    const float* attn_b = (const float*)d_in[4];
    const float* fc_w   = (const float*)d_in[5];
    const float* fc_b   = (const float*)d_in[6];
    const float* gamma  = (const float*)d_in[7];
    const float* beta   = (const float*)d_in[8];
    float* out = (float*)d_out;

    float* ws      = (float*)d_ws;
    float* pl      = ws;                          // [2048]
    float* pc      = pl + NPART;                  // [2048][768]
    float* context = pc + (size_t)NPART * H;      // [32][768]

    pool_partial<<<dim3(NPART), 256, 0, stream>>>(hs, mask, boost, attn_w, attn_b,
                                                  pl, pc);
    pool_combine<<<dim3(H / 256, B), 256, 0, stream>>>(pl, pc, context);
    fc_bn_relu<<<dim3(H / 256, B), 256, 0, stream>>>(context, gamma, beta,
                                                     fc_w, fc_b, out);
}